// Round 1
// baseline (527.528 us; speedup 1.0000x reference)
//
#include <hip/hip_runtime.h>

// Problem constants
constexpr int Bn   = 32;
constexpr int CIN  = 64;
constexpr int Lx   = 8192;
constexpr int L1   = 8190;   // length after kw=3,d=1 VALID conv
constexpr int LOUT = 8186;   // final output length
constexpr int NCH  = 384;    // 3 * 128 output channels

constexpr int TB = 256;      // threads per block
constexpr int TT = 256;      // time-tile per block
constexpr int NTILES = (LOUT + TT - 1) / TT;  // 32

// LDS array widths (all divisible by 4 -> every row 16B aligned)
constexpr int W7v   = TT + 4;   // h7   covers s in [t0,   t0+TT+4)
constexpr int W10Av = TT + 8;   // h10a covers s in [t0-4, t0+TT+4)
constexpr int W15Av = TT + 12;  // h15a covers s in [t0-8, t0+TT+4)
constexpr int W10Bv = TT + 4;   // h10b covers u in [t0-4, t0+TT)
constexpr int W15Bv = TT + 8;   // h15b covers u in [t0-8, t0+TT)

// Pre-transpose stage-1 weights into ws: layout [ci][64] with first 54 =
// (k,j) -> k*3+j, k = 0..5: w7_1 row k, 6..11: w10_1, 12..17: w15_1.
// Stride 64 floats = 256 B so each ci-chunk is wide-s_load friendly.
__global__ void prep_weights(const float* __restrict__ w7_1,
                             const float* __restrict__ w10_1,
                             const float* __restrict__ w15_1,
                             float* __restrict__ ws) {
    int idx = blockIdx.x * blockDim.x + threadIdx.x;
    if (idx >= 64 * 54) return;
    int ci = idx / 54, r = idx % 54;
    int k = r / 3, j = r % 3;
    const float* src = (k < 6) ? w7_1 : ((k < 12) ? w10_1 : w15_1);
    int kk = (k < 6) ? k : ((k < 12) ? k - 6 : k - 12);
    ws[ci * 64 + r] = src[kk * 192 + ci * 3 + j];
}

__device__ __forceinline__ void store4(float* __restrict__ op, int t,
                                       float a0, float a1, float a2, float a3) {
    // op points at row start (8B-aligned); t is multiple of 4 -> float2 ok
    a0 = fmaxf(a0, 0.f); a1 = fmaxf(a1, 0.f);
    a2 = fmaxf(a2, 0.f); a3 = fmaxf(a3, 0.f);
    if (t + 3 < LOUT) {
        *(float2*)(op + t)     = make_float2(a0, a1);
        *(float2*)(op + t + 2) = make_float2(a2, a3);
    } else {
        if (t     < LOUT) op[t]     = a0;
        if (t + 1 < LOUT) op[t + 1] = a1;
        if (t + 2 < LOUT) op[t + 2] = a2;
        if (t + 3 < LOUT) op[t + 3] = a3;
    }
}

__global__ __launch_bounds__(TB)
void fused_inception(const float* __restrict__ x,
                     const float* __restrict__ wS1,   // d_ws, [64][64]
                     const float* __restrict__ w7_3,
                     const float* __restrict__ w10_3,
                     const float* __restrict__ w10_5,
                     const float* __restrict__ w15_3,
                     const float* __restrict__ w15_5,
                     float* __restrict__ out) {
    __shared__ float h7  [6 * W7v];
    __shared__ float h10a[6 * W10Av];
    __shared__ float h15a[6 * W15Av];
    __shared__ float h10b[6 * W10Bv];
    __shared__ float h15b[6 * W15Bv];

    const int tid  = threadIdx.x;
    const int tile = blockIdx.x;
    const int b    = blockIdx.y;
    const int t0   = tile * TT;
    const float* xb = x + (size_t)b * CIN * Lx;

    // ---------------- stage 1: three 64->6 convs (kw=3, d=1) ----------------
    for (int p = tid; p < TT + 12; p += TB) {
        const int s = t0 - 8 + p;
        float acc[18];
        #pragma unroll
        for (int k = 0; k < 18; ++k) acc[k] = 0.f;
        if (s >= 0 && s < L1) {
            const float* xr = xb + s;
            for (int ci = 0; ci < CIN; ++ci) {
                const float x0 = xr[ci * Lx];
                const float x1 = xr[ci * Lx + 1];
                const float x2 = xr[ci * Lx + 2];
                const float* wr = wS1 + ci * 64;   // uniform -> s_load
                #pragma unroll
                for (int k = 0; k < 18; ++k) {
                    acc[k] = fmaf(wr[k * 3 + 0], x0, acc[k]);
                    acc[k] = fmaf(wr[k * 3 + 1], x1, acc[k]);
                    acc[k] = fmaf(wr[k * 3 + 2], x2, acc[k]);
                }
            }
            #pragma unroll
            for (int k = 0; k < 18; ++k) acc[k] = fmaxf(acc[k], 0.f);
        }
        if (p >= 8) {
            #pragma unroll
            for (int c = 0; c < 6; ++c) h7[c * W7v + (p - 8)] = acc[c];
        }
        if (p >= 4) {
            #pragma unroll
            for (int c = 0; c < 6; ++c) h10a[c * W10Av + (p - 4)] = acc[6 + c];
        }
        #pragma unroll
        for (int c = 0; c < 6; ++c) h15a[c * W15Av + p] = acc[12 + c];
    }
    __syncthreads();

    // ---------------- stage 2: mid 6->6 convs (kw=3, d=2) ----------------
    for (int p = tid; p < W10Bv; p += TB) {
        const int u = t0 - 4 + p;
        float v[18];
        #pragma unroll
        for (int c = 0; c < 6; ++c)
            #pragma unroll
            for (int j = 0; j < 3; ++j)
                v[c * 3 + j] = h10a[c * W10Av + p + 2 * j];
        #pragma unroll
        for (int k = 0; k < 6; ++k) {
            float a = 0.f;
            #pragma unroll
            for (int r = 0; r < 18; ++r) a = fmaf(w10_3[k * 18 + r], v[r], a);
            h10b[k * W10Bv + p] = (u >= 0) ? fmaxf(a, 0.f) : 0.f;  // causal pad
        }
    }
    for (int p = tid; p < W15Bv; p += TB) {
        const int u = t0 - 8 + p;
        float v[18];
        #pragma unroll
        for (int c = 0; c < 6; ++c)
            #pragma unroll
            for (int j = 0; j < 3; ++j)
                v[c * 3 + j] = h15a[c * W15Av + p + 2 * j];
        #pragma unroll
        for (int k = 0; k < 6; ++k) {
            float a = 0.f;
            #pragma unroll
            for (int r = 0; r < 18; ++r) a = fmaf(w15_3[k * 18 + r], v[r], a);
            h15b[k * W15Bv + p] = (u >= 0) ? fmaxf(a, 0.f) : 0.f;  // causal pad
        }
    }
    __syncthreads();

    // ---------------- stage 3: three 6->128 final convs + relu + store -----
    const int tq = tid & 63;        // lane: 4 consecutive t per lane
    const int wv = tid >> 6;        // wave: 32 output channels per wave
    const int tt = tq * 4;
    const int tglob = t0 + tt;

    // branch 7: kw=3, d=2 over h7; out channels [0,128)
    {
        float v[6][8];
        #pragma unroll
        for (int c = 0; c < 6; ++c) {
            float4 A = *(const float4*)&h7[c * W7v + tt];
            float4 Bv = *(const float4*)&h7[c * W7v + tt + 4];
            v[c][0] = A.x; v[c][1] = A.y; v[c][2] = A.z; v[c][3] = A.w;
            v[c][4] = Bv.x; v[c][5] = Bv.y; v[c][6] = Bv.z; v[c][7] = Bv.w;
        }
        for (int oi = 0; oi < 32; ++oi) {
            const int oc = wv * 32 + oi;
            const float* wr = w7_3 + oc * 18;      // wave-uniform -> s_load
            float a0 = 0, a1 = 0, a2 = 0, a3 = 0;
            #pragma unroll
            for (int c = 0; c < 6; ++c)
                #pragma unroll
                for (int j = 0; j < 3; ++j) {
                    const float w = wr[c * 3 + j];
                    a0 = fmaf(w, v[c][0 + 2 * j], a0);
                    a1 = fmaf(w, v[c][1 + 2 * j], a1);
                    a2 = fmaf(w, v[c][2 + 2 * j], a2);
                    a3 = fmaf(w, v[c][3 + 2 * j], a3);
                }
            float* op = out + ((size_t)b * NCH + oc) * LOUT;
            store4(op, tglob, a0, a1, a2, a3);
        }
    }
    // branch 10: kw=2, d=4, causal pad 4 over h10b; out channels [128,256)
    {
        float v[6][8];
        #pragma unroll
        for (int c = 0; c < 6; ++c) {
            float4 A = *(const float4*)&h10b[c * W10Bv + tt];
            float4 Bv = *(const float4*)&h10b[c * W10Bv + tt + 4];
            v[c][0] = A.x; v[c][1] = A.y; v[c][2] = A.z; v[c][3] = A.w;
            v[c][4] = Bv.x; v[c][5] = Bv.y; v[c][6] = Bv.z; v[c][7] = Bv.w;
        }
        for (int oi = 0; oi < 32; ++oi) {
            const int oc = wv * 32 + oi;
            const float* wr = w10_5 + oc * 12;
            float a0 = 0, a1 = 0, a2 = 0, a3 = 0;
            #pragma unroll
            for (int c = 0; c < 6; ++c) {
                const float w0 = wr[c * 2 + 0];
                const float w1 = wr[c * 2 + 1];
                a0 = fmaf(w0, v[c][0], a0); a0 = fmaf(w1, v[c][4], a0);
                a1 = fmaf(w0, v[c][1], a1); a1 = fmaf(w1, v[c][5], a1);
                a2 = fmaf(w0, v[c][2], a2); a2 = fmaf(w1, v[c][6], a2);
                a3 = fmaf(w0, v[c][3], a3); a3 = fmaf(w1, v[c][7], a3);
            }
            float* op = out + ((size_t)b * NCH + 128 + oc) * LOUT;
            store4(op, tglob, a0, a1, a2, a3);
        }
    }
    // branch 15: kw=3, d=4, causal pad 8 over h15b; out channels [256,384)
    {
        float v[6][12];
        #pragma unroll
        for (int c = 0; c < 6; ++c) {
            float4 A = *(const float4*)&h15b[c * W15Bv + tt];
            float4 Bv = *(const float4*)&h15b[c * W15Bv + tt + 4];
            float4 Cv = *(const float4*)&h15b[c * W15Bv + tt + 8];
            v[c][0] = A.x;  v[c][1] = A.y;  v[c][2] = A.z;  v[c][3] = A.w;
            v[c][4] = Bv.x; v[c][5] = Bv.y; v[c][6] = Bv.z; v[c][7] = Bv.w;
            v[c][8] = Cv.x; v[c][9] = Cv.y; v[c][10] = Cv.z; v[c][11] = Cv.w;
        }
        for (int oi = 0; oi < 32; ++oi) {
            const int oc = wv * 32 + oi;
            const float* wr = w15_5 + oc * 18;
            float a0 = 0, a1 = 0, a2 = 0, a3 = 0;
            #pragma unroll
            for (int c = 0; c < 6; ++c)
                #pragma unroll
                for (int j = 0; j < 3; ++j) {
                    const float w = wr[c * 3 + j];
                    a0 = fmaf(w, v[c][0 + 4 * j], a0);
                    a1 = fmaf(w, v[c][1 + 4 * j], a1);
                    a2 = fmaf(w, v[c][2 + 4 * j], a2);
                    a3 = fmaf(w, v[c][3 + 4 * j], a3);
                }
            float* op = out + ((size_t)b * NCH + 256 + oc) * LOUT;
            store4(op, tglob, a0, a1, a2, a3);
        }
    }
}

extern "C" void kernel_launch(void* const* d_in, const int* in_sizes, int n_in,
                              void* d_out, int out_size, void* d_ws, size_t ws_size,
                              hipStream_t stream) {
    const float* x     = (const float*)d_in[0];
    const float* w7_1  = (const float*)d_in[1];
    const float* w7_3  = (const float*)d_in[2];
    const float* w10_1 = (const float*)d_in[3];
    const float* w10_3 = (const float*)d_in[4];
    const float* w10_5 = (const float*)d_in[5];
    const float* w15_1 = (const float*)d_in[6];
    const float* w15_3 = (const float*)d_in[7];
    const float* w15_5 = (const float*)d_in[8];
    float* out = (float*)d_out;
    float* ws  = (float*)d_ws;   // 64*64 floats = 16 KB used

    prep_weights<<<dim3(14), dim3(256), 0, stream>>>(w7_1, w10_1, w15_1, ws);
    fused_inception<<<dim3(NTILES, Bn), dim3(TB), 0, stream>>>(
        x, ws, w7_3, w10_3, w10_5, w15_3, w15_5, out);
}